// Round 6
// baseline (317.135 us; speedup 1.0000x reference)
//
#include <hip/hip_runtime.h>
#include <hip/hip_bf16.h>
#include <math.h>

#define N_PTS 8192
#define S_PTS 4096

// Double-precision pair distance, rounded to float (accurate output values).
__device__ __forceinline__ float pair_dist_d(const float4 a, const float4 b) {
    double ax = a.x, ay = a.y, az = a.z;
    double bx = b.x, by = b.y, bz = b.z;
    double dx = ax - bx, dy = ay - by, dz = az - bz;
    double d2 = dx * dx + dy * dy + dz * dz;
    return d2 > 0.0 ? (float)sqrt(d2) : 0.0f;
}

// Strict fp32 GRAM-formula distance, numpy-ordered, no fma contraction:
//   dot = ((x*x' + y*y') + z*z');  d2 = (sq_a + sq_b) - 2*dot;
//   d2 = max(d2, 0);  D = d2 > 0 ? sqrt(d2) : 0.
// This replicates the reference cdist bit-for-bit (including the d2<=0
// collapse-to-zero quirk for very close pairs, which ties the self-point).
__device__ __forceinline__ float dist_f32_gram(const float4 a, const float4 b) {
    float dot = __fadd_rn(__fadd_rn(__fmul_rn(a.x, b.x), __fmul_rn(a.y, b.y)),
                          __fmul_rn(a.z, b.z));
    float d2 = __fsub_rn(__fadd_rn(a.w, b.w), __fmul_rn(2.0f, dot));
    d2 = fmaxf(d2, 0.0f);
    return d2 > 0.0f ? __fsqrt_rn(d2) : 0.0f;
}

// ---------------------------------------------------------------- stage
__global__ __launch_bounds__(256) void stage_kernel(
        const float* __restrict__ xyz, const int* __restrict__ sidx,
        float4* __restrict__ cb, float4* __restrict__ ca,
        float* __restrict__ out_xyz_s) {
    int i = blockIdx.x * blockDim.x + threadIdx.x;
    if (i < N_PTS) {
        float x = xyz[i * 3 + 0], y = xyz[i * 3 + 1], z = xyz[i * 3 + 2];
        // strict fp32 sum-of-squares, numpy order (no fma)
        float sq = __fadd_rn(__fadd_rn(__fmul_rn(x, x), __fmul_rn(y, y)),
                             __fmul_rn(z, z));
        cb[i] = make_float4(x, y, z, sq);
    }
    if (i < S_PTS) {
        int si = sidx[i];
        float x = xyz[si * 3 + 0], y = xyz[si * 3 + 1], z = xyz[si * 3 + 2];
        float sq = __fadd_rn(__fadd_rn(__fmul_rn(x, x), __fmul_rn(y, y)),
                             __fmul_rn(z, z));
        ca[i] = make_float4(x, y, z, sq);
        out_xyz_s[i * 3 + 0] = x;
        out_xyz_s[i * 3 + 1] = y;
        out_xyz_s[i * 3 + 2] = z;
    }
}

// ---------------------------------------------------------------- knn core
// Rank by strict fp32-gram D; ties (equal fp32 D, incl. the D==0 collapse
// set) break toward LOWER index, matching lax.top_k / stable argsort.
// key = (float_bits(D) << 32) | idx;  D >= 0 so bits are order-monotone.
template <int KOUT>
__device__ __forceinline__ unsigned long long knn_topk(
        const float4 q, const float4* __restrict__ cand, int ncand, int lane) {
    unsigned long long L[KOUT];
#pragma unroll
    for (int j = 0; j < KOUT; ++j) L[j] = ~0ull;

    for (int c = lane; c < ncand; c += 64) {
        float4 p = cand[c];
        float Df = dist_f32_gram(q, p);
        unsigned long long key =
            ((unsigned long long)__float_as_uint(Df) << 32) |
            (unsigned long long)(unsigned)c;
        if (key < L[KOUT - 1]) {
#pragma unroll
            for (int j = KOUT - 1; j >= 1; --j)
                L[j] = (key < L[j - 1]) ? L[j - 1] : ((key < L[j]) ? key : L[j]);
            L[0] = (key < L[0]) ? key : L[0];
        }
    }

    // wave-wide merge: KOUT rounds of u64 min-reduce + winner pops head
    unsigned long long myres = ~0ull;
#pragma unroll
    for (int r = 0; r < KOUT; ++r) {
        unsigned long long m = L[0];
#pragma unroll
        for (int off = 32; off >= 1; off >>= 1) {
            unsigned long long o = __shfl_xor(m, off, 64);
            m = (o < m) ? o : m;
        }
        if (lane == r) myres = m;
        if (L[0] == m) {  // unique winner (keys contain unique idx)
#pragma unroll
            for (int j = 0; j < KOUT - 1; ++j) L[j] = L[j + 1];
            L[KOUT - 1] = ~0ull;
        }
    }
    return myres;
}

// ---------------------------------------------------------------- knn before (top-4 at sampled points)
__global__ __launch_bounds__(64) void knn_before_kernel(
        const float4* __restrict__ cb, const int* __restrict__ sidx,
        int* __restrict__ a_before, float* __restrict__ intra_before) {
    int s = blockIdx.x;
    int lane = threadIdx.x;
    float4 q = cb[sidx[s]];
    unsigned long long r = knn_topk<4>(q, cb, N_PTS, lane);
    int idx = (int)(r & 0xffffffffull);
    if (lane < 4) a_before[s * 4 + lane] = idx;
    if (lane >= 1 && lane < 4) intra_before[s * 6 + (lane - 1)] = pair_dist_d(q, cb[idx]);
    int i1 = __shfl(idx, 1, 64);
    int i2 = __shfl(idx, 2, 64);
    int i3 = __shfl(idx, 3, 64);
    if (lane < 3) {  // pairs (1,2),(1,3),(2,3)
        int pa = (lane == 2) ? i2 : i1;
        int pb = (lane == 0) ? i2 : i3;
        intra_before[s * 6 + 3 + lane] = pair_dist_d(cb[pa], cb[pb]);
    }
}

// ---------------------------------------------------------------- knn after (top-16 among sampled points)
__global__ __launch_bounds__(64) void knn_after_kernel(
        const float4* __restrict__ ca, int* __restrict__ ni_i,
        float* __restrict__ intra_after, float* __restrict__ out_ni) {
    int s = blockIdx.x;
    int lane = threadIdx.x;
    float4 q = ca[s];
    unsigned long long r = knn_topk<16>(q, ca, S_PTS, lane);
    int idx = (int)(r & 0xffffffffull);
    if (lane < 16) {
        ni_i[s * 16 + lane] = idx;
        out_ni[s * 16 + lane] = (float)idx;
    }
    if (lane >= 1 && lane < 4) intra_after[s * 6 + (lane - 1)] = pair_dist_d(q, ca[idx]);
    int i1 = __shfl(idx, 1, 64);
    int i2 = __shfl(idx, 2, 64);
    int i3 = __shfl(idx, 3, 64);
    if (lane < 3) {
        int pa = (lane == 2) ? i2 : i1;
        int pb = (lane == 0) ? i2 : i3;
        intra_after[s * 6 + 3 + lane] = pair_dist_d(ca[pa], ca[pb]);
    }
}

// ---------------------------------------------------------------- rf_after assembly + adf
__global__ __launch_bounds__(64) void assemble_kernel(
        const float4* __restrict__ ca, const float4* __restrict__ cb,
        const int* __restrict__ ni_i, const float* __restrict__ intra_after,
        const int* __restrict__ a_before, const float* __restrict__ intra_before,
        const int* __restrict__ sidx,
        float* __restrict__ out_rf, float* __restrict__ adf) {
    __shared__ int s_ni[16];
    __shared__ float s_rf[16 * 28];
    __shared__ float s_ia[6];
    int s = blockIdx.x;
    int t = threadIdx.x;
    if (t < 16) s_ni[t] = ni_i[s * 16 + t];
    if (t < 6) s_ia[t] = intra_after[s * 6 + t];
    __syncthreads();

    // inter block of rf: rf[s,k,12+p*4+q] = D_after(ni[s,p], ni[ni[s,k],q])
    int k = t >> 2, qq = t & 3;
    int nai_q = ni_i[s_ni[k] * 16 + qq];
    float4 pq = ca[nai_q];
#pragma unroll
    for (int p = 0; p < 4; ++p) {
        float4 pp = ca[s_ni[p]];
        s_rf[k * 28 + 12 + p * 4 + qq] = pair_dist_d(pp, pq);
    }
    // center intra (ch 0..5) + neighbor intra (ch 6..11)
    for (int idx = t; idx < 16 * 12; idx += 64) {
        int kk = idx / 12, c = idx % 12;
        float v = (c < 6) ? s_ia[c] : intra_after[s_ni[kk] * 6 + (c - 6)];
        s_rf[kk * 28 + c] = v;
    }
    // adf: [intra_before(6), intra_after(6), inter(16)]
    if (t < 16) {
        int p = t >> 2, q2 = t & 3;
        int ib = a_before[s * 4 + p];
        int ia = sidx[s_ni[q2]];
        adf[s * 28 + 12 + t] = pair_dist_d(cb[ib], cb[ia]);
    } else if (t >= 32 && t < 38) {
        adf[s * 28 + (t - 32)] = intra_before[s * 6 + (t - 32)];
    } else if (t >= 40 && t < 46) {
        adf[s * 28 + 6 + (t - 40)] = s_ia[t - 40];
    }
    __syncthreads();
    const int base = s * 16 * 28;
    for (int idx = t; idx < 16 * 28; idx += 64) out_rf[base + idx] = s_rf[idx];
}

// ---------------------------------------------------------------- mlp1: y_w,y_b = adf@W + b  (stored [C][S])
__global__ __launch_bounds__(256) void mlp1_kernel(
        const float* __restrict__ adf,
        const float* __restrict__ Ww, const float* __restrict__ bw,
        const float* __restrict__ Wb, const float* __restrict__ bb,
        float* __restrict__ y_w, float* __restrict__ y_b) {
    __shared__ float sW[28 * 64], sB[28 * 64];
    int t = threadIdx.x;
    for (int i = t; i < 28 * 64; i += 256) { sW[i] = Ww[i]; sB[i] = Wb[i]; }
    __syncthreads();
    int s = blockIdx.x * 256 + t;
    float a[28];
#pragma unroll
    for (int k2 = 0; k2 < 28; ++k2) a[k2] = adf[s * 28 + k2];
    for (int c = 0; c < 64; ++c) {
        float aw = bw[c], ab = bb[c];
#pragma unroll
        for (int k2 = 0; k2 < 28; ++k2) {
            aw = fmaf(a[k2], sW[k2 * 64 + c], aw);
            ab = fmaf(a[k2], sB[k2 * 64 + c], ab);
        }
        y_w[c * 4096 + s] = aw;
        y_b[c * 4096 + s] = ab;
    }
}

// ---------------------------------------------------------------- batchnorm stats: block per channel
__global__ __launch_bounds__(256) void stats_kernel(
        const float* __restrict__ y,  // [C][4096]
        const float* __restrict__ g0, const float* __restrict__ be0,
        const float* __restrict__ g1, const float* __restrict__ be1, int csplit,
        float* __restrict__ scale, float* __restrict__ shift) {
    int c = blockIdx.x;
    const float* p = y + c * 4096;
    float s1 = 0.0f, s2 = 0.0f;
    for (int i = threadIdx.x; i < 4096; i += 256) {
        float v = p[i];
        s1 += v;
        s2 = fmaf(v, v, s2);
    }
    __shared__ float l1[256], l2[256];
    l1[threadIdx.x] = s1;
    l2[threadIdx.x] = s2;
    __syncthreads();
    for (int off = 128; off; off >>= 1) {
        if (threadIdx.x < off) {
            l1[threadIdx.x] += l1[threadIdx.x + off];
            l2[threadIdx.x] += l2[threadIdx.x + off];
        }
        __syncthreads();
    }
    if (threadIdx.x == 0) {
        float mean = l1[0] * (1.0f / 4096.0f);
        float var = l2[0] * (1.0f / 4096.0f) - mean * mean;
        float g = (c < csplit) ? g0[c] : g1[c - csplit];
        float be = (c < csplit) ? be0[c] : be1[c - csplit];
        float sc = g / sqrtf(var + 1e-5f);
        scale[c] = sc;
        shift[c] = be - mean * sc;
    }
}

// ---------------------------------------------------------------- mlp2: f1 = lrelu(feat*w + b); y_o = [f1,adf]@Wo + bo
__global__ __launch_bounds__(256) void mlp2_kernel(
        const float* __restrict__ y_wb,
        const float* __restrict__ scale1, const float* __restrict__ shift1,
        const float* __restrict__ feature, const int* __restrict__ sidx,
        const float* __restrict__ adf,
        const float* __restrict__ Wo, const float* __restrict__ bo,
        float* __restrict__ y_o) {
    __shared__ float sW[92 * 128];
    int t = threadIdx.x;
    for (int i = t; i < 92 * 128; i += 256) sW[i] = Wo[i];
    __syncthreads();
    int s = blockIdx.x * 256 + t;
    int si = sidx[s];
    float cat[92];
#pragma unroll
    for (int c = 0; c < 64; ++c) {
        float wv = fmaf(y_wb[c * 4096 + s], scale1[c], shift1[c]);
        float bv = fmaf(y_wb[(64 + c) * 4096 + s], scale1[64 + c], shift1[64 + c]);
        float f = feature[si * 64 + c];
        float v = fmaf(f, wv, bv);
        cat[c] = v >= 0.0f ? v : 0.2f * v;
    }
#pragma unroll
    for (int k2 = 0; k2 < 28; ++k2) cat[64 + k2] = adf[s * 28 + k2];
    for (int j = 0; j < 128; ++j) {
        float acc = bo[j];
#pragma unroll
        for (int c = 0; c < 92; ++c) acc = fmaf(cat[c], sW[c * 128 + j], acc);
        y_o[j * 4096 + s] = acc;
    }
}

// ---------------------------------------------------------------- final: normalize + lrelu, write feat
__global__ __launch_bounds__(256) void final_kernel(
        const float* __restrict__ y_o,
        const float* __restrict__ scale, const float* __restrict__ shift,
        float* __restrict__ out_feat) {
    int tid = blockIdx.x * 256 + threadIdx.x;  // 0..524287
    int j = tid >> 12;
    int s = tid & 4095;
    float v = fmaf(y_o[tid], scale[j], shift[j]);
    v = v >= 0.0f ? v : 0.2f * v;
    out_feat[s * 128 + j] = v;
}

// ----------------------------------------------------------------
extern "C" void kernel_launch(void* const* d_in, const int* in_sizes, int n_in,
                              void* d_out, int out_size, void* d_ws, size_t ws_size,
                              hipStream_t stream) {
    const float* xyz = (const float*)d_in[0];
    const float* feature = (const float*)d_in[1];
    const int* sidx = (const int*)d_in[2];
    const float* Ww = (const float*)d_in[3];
    const float* bw = (const float*)d_in[4];
    const float* gw = (const float*)d_in[5];
    const float* betaw = (const float*)d_in[6];
    const float* Wb = (const float*)d_in[7];
    const float* bb = (const float*)d_in[8];
    const float* gb = (const float*)d_in[9];
    const float* betab = (const float*)d_in[10];
    const float* Wo = (const float*)d_in[11];
    const float* bo = (const float*)d_in[12];
    const float* go = (const float*)d_in[13];
    const float* betao = (const float*)d_in[14];

    float* out = (float*)d_out;
    float* out_xyz = out;                                  // 4096*3
    float* out_feat = out + 12288;                         // 4096*128
    float* out_rf = out + 12288 + 524288;                  // 4096*16*28
    float* out_ni = out + 12288 + 524288 + 1835008;        // 4096*16

    float* ws = (float*)d_ws;
    float4* cb = (float4*)ws;                  // 8192 float4
    float4* ca = (float4*)(ws + 32768);        // 4096 float4
    int* a_before = (int*)(ws + 49152);        // 4096*4
    float* intra_before = ws + 65536;          // 4096*6
    int* ni_i = (int*)(ws + 90112);            // 4096*16
    float* intra_after = ws + 155648;          // 4096*6
    float* adf = ws + 180224;                  // 4096*28
    float* y_wb = ws + 294912;                 // 128*4096 (y_w then y_b)
    float* y_o = ws + 819200;                  // 128*4096
    float* scale1 = ws + 1343488;              // 128
    float* shift1 = ws + 1343616;              // 128
    float* scale_o = ws + 1343744;             // 128
    float* shift_o = ws + 1343872;             // 128

    stage_kernel<<<32, 256, 0, stream>>>(xyz, sidx, cb, ca, out_xyz);
    knn_before_kernel<<<4096, 64, 0, stream>>>(cb, sidx, a_before, intra_before);
    knn_after_kernel<<<4096, 64, 0, stream>>>(ca, ni_i, intra_after, out_ni);
    assemble_kernel<<<4096, 64, 0, stream>>>(ca, cb, ni_i, intra_after, a_before,
                                             intra_before, sidx, out_rf, adf);
    mlp1_kernel<<<16, 256, 0, stream>>>(adf, Ww, bw, Wb, bb, y_wb, y_wb + 64 * 4096);
    stats_kernel<<<128, 256, 0, stream>>>(y_wb, gw, betaw, gb, betab, 64, scale1, shift1);
    mlp2_kernel<<<16, 256, 0, stream>>>(y_wb, scale1, shift1, feature, sidx, adf, Wo, bo, y_o);
    stats_kernel<<<128, 256, 0, stream>>>(y_o, go, betao, go, betao, 128, scale_o, shift_o);
    final_kernel<<<2048, 256, 0, stream>>>(y_o, scale_o, shift_o, out_feat);
}

// Round 7
// 260.758 us; speedup vs baseline: 1.2162x; 1.2162x over previous
//
#include <hip/hip_runtime.h>
#include <hip/hip_bf16.h>
#include <math.h>

#define N_PTS 8192
#define S_PTS 4096

// Double-precision pair distance, rounded to float (accurate output values).
__device__ __forceinline__ float pair_dist_d(const float4 a, const float4 b) {
    double ax = a.x, ay = a.y, az = a.z;
    double bx = b.x, by = b.y, bz = b.z;
    double dx = ax - bx, dy = ay - by, dz = az - bz;
    double d2 = dx * dx + dy * dy + dz * dz;
    return d2 > 0.0 ? (float)sqrt(d2) : 0.0f;
}

// ---------------------------------------------------------------- stage
__global__ __launch_bounds__(256) void stage_kernel(
        const float* __restrict__ xyz, const int* __restrict__ sidx,
        float4* __restrict__ cb, float4* __restrict__ ca,
        float* __restrict__ out_xyz_s) {
    int i = blockIdx.x * blockDim.x + threadIdx.x;
    if (i < N_PTS) {
        float x = xyz[i * 3 + 0], y = xyz[i * 3 + 1], z = xyz[i * 3 + 2];
        // strict fp32 sum-of-squares, numpy order (no fma)
        float sq = __fadd_rn(__fadd_rn(__fmul_rn(x, x), __fmul_rn(y, y)),
                             __fmul_rn(z, z));
        cb[i] = make_float4(x, y, z, sq);
    }
    if (i < S_PTS) {
        int si = sidx[i];
        float x = xyz[si * 3 + 0], y = xyz[si * 3 + 1], z = xyz[si * 3 + 2];
        float sq = __fadd_rn(__fadd_rn(__fmul_rn(x, x), __fmul_rn(y, y)),
                             __fmul_rn(z, z));
        ca[i] = make_float4(x, y, z, sq);
        out_xyz_s[i * 3 + 0] = x;
        out_xyz_s[i * 3 + 1] = y;
        out_xyz_s[i * 3 + 2] = z;
    }
}

// ---------------------------------------------------------------- knn scan + wave merge
// Rank by strict fp32-gram D (replicates reference cdist bit-exactly, incl.
// the d2<=0 collapse quirk); ties break toward LOWER index (stable top_k).
// Per-lane: (u32 Dbits, u32 idx) sorted insert ladder; strict < on Dbits is
// stable because each lane scans in increasing idx order. Merge on packed
// u64 (Dbits<<32 | idx) = (D, idx) lexicographic.
template <int KOUT, int ITERS>
__device__ __forceinline__ unsigned long long knn_wave_scan_merge(
        const float4 q, const float4* __restrict__ cand, int c0, int lane) {
    unsigned Lk[KOUT], Li[KOUT];
#pragma unroll
    for (int j = 0; j < KOUT; ++j) { Lk[j] = 0xFFFFFFFFu; Li[j] = 0xFFFFFFFFu; }

    int c = c0 + lane;
    for (int tt = 0; tt < ITERS; ++tt, c += 64) {
        float4 p = cand[c];
        float dot = __fadd_rn(__fadd_rn(__fmul_rn(q.x, p.x), __fmul_rn(q.y, p.y)),
                              __fmul_rn(q.z, p.z));
        float d2 = __fsub_rn(__fadd_rn(q.w, p.w), __fmul_rn(2.0f, dot));
        d2 = fmaxf(d2, 0.0f);
        float Df = d2 > 0.0f ? __fsqrt_rn(d2) : 0.0f;
        unsigned kb = __float_as_uint(Df);
        if (kb < Lk[KOUT - 1]) {
#pragma unroll
            for (int j = KOUT - 1; j >= 1; --j) {
                bool up  = kb < Lk[j - 1];
                bool ins = kb < Lk[j];
                Lk[j] = up ? Lk[j - 1] : (ins ? kb : Lk[j]);
                Li[j] = up ? Li[j - 1] : (ins ? (unsigned)c : Li[j]);
            }
            bool i0 = kb < Lk[0];
            Lk[0] = i0 ? kb : Lk[0];
            Li[0] = i0 ? (unsigned)c : Li[0];
        }
    }

    unsigned long long Lu[KOUT];
#pragma unroll
    for (int j = 0; j < KOUT; ++j)
        Lu[j] = ((unsigned long long)Lk[j] << 32) | (unsigned long long)Li[j];

    // wave-wide merge: KOUT rounds of u64 min-reduce + winner pops head
    unsigned long long myres = ~0ull;
#pragma unroll
    for (int r = 0; r < KOUT; ++r) {
        unsigned long long m = Lu[0];
#pragma unroll
        for (int off = 32; off >= 1; off >>= 1) {
            unsigned long long o = __shfl_xor(m, off, 64);
            m = (o < m) ? o : m;
        }
        if (lane == r) myres = m;
        if (Lu[0] == m) {  // unique winner (keys contain unique idx)
#pragma unroll
            for (int j = 0; j < KOUT - 1; ++j) Lu[j] = Lu[j + 1];
            Lu[KOUT - 1] = ~0ull;
        }
    }
    return myres;
}

// block-level merge by wave 0: each lane holds one candidate key (or ~0)
template <int KOUT>
__device__ __forceinline__ unsigned long long block_merge(
        unsigned long long v, int lane) {
    unsigned long long res = ~0ull;
#pragma unroll
    for (int r = 0; r < KOUT; ++r) {
        unsigned long long m = v;
#pragma unroll
        for (int off = 32; off >= 1; off >>= 1) {
            unsigned long long o = __shfl_xor(m, off, 64);
            m = (o < m) ? o : m;
        }
        if (lane == r) res = m;
        if (v == m) v = ~0ull;
    }
    return res;
}

// ---------------------------------------------------------------- merged knn
// blocks [0, S_PTS): "after" queries (top-16 over ca, 4096 cands)
// blocks [S_PTS, 2*S_PTS): "before" queries (top-4 over cb, 8192 cands)
// 4 waves per block, each scans a contiguous quarter lane-strided.
__global__ __launch_bounds__(256, 4) void knn_kernel(
        const float4* __restrict__ cb, const float4* __restrict__ ca,
        const int* __restrict__ sidx,
        int* __restrict__ a_before, float* __restrict__ intra_before,
        int* __restrict__ ni_i, float* __restrict__ intra_after,
        float* __restrict__ out_ni) {
    __shared__ unsigned long long sm[64];
    int t = threadIdx.x, wid = t >> 6, lane = t & 63;
    int bid = blockIdx.x;
    if (bid < S_PTS) {
        int s = bid;
        float4 q = ca[s];
        unsigned long long r = knn_wave_scan_merge<16, 16>(q, ca, wid * 1024, lane);
        if (lane < 16) sm[wid * 16 + lane] = r;
        __syncthreads();
        if (wid == 0) {
            unsigned long long res = block_merge<16>(sm[lane], lane);
            int idx = (int)(res & 0xffffffffull);
            if (lane < 16) {
                ni_i[s * 16 + lane] = idx;
                out_ni[s * 16 + lane] = (float)idx;
            }
            if (lane >= 1 && lane < 4)
                intra_after[s * 6 + (lane - 1)] = pair_dist_d(q, ca[idx]);
            int i1 = __shfl(idx, 1, 64);
            int i2 = __shfl(idx, 2, 64);
            int i3 = __shfl(idx, 3, 64);
            if (lane < 3) {  // pairs (1,2),(1,3),(2,3)
                int pa = (lane == 2) ? i2 : i1;
                int pb = (lane == 0) ? i2 : i3;
                intra_after[s * 6 + 3 + lane] = pair_dist_d(ca[pa], ca[pb]);
            }
        }
    } else {
        int s = bid - S_PTS;
        float4 q = cb[sidx[s]];
        unsigned long long r = knn_wave_scan_merge<4, 32>(q, cb, wid * 2048, lane);
        if (lane < 4) sm[wid * 4 + lane] = r;
        __syncthreads();
        if (wid == 0) {
            unsigned long long v = (lane < 16) ? sm[lane] : ~0ull;
            unsigned long long res = block_merge<4>(v, lane);
            int idx = (int)(res & 0xffffffffull);
            if (lane < 4) a_before[s * 4 + lane] = idx;
            if (lane >= 1 && lane < 4)
                intra_before[s * 6 + (lane - 1)] = pair_dist_d(q, cb[idx]);
            int i1 = __shfl(idx, 1, 64);
            int i2 = __shfl(idx, 2, 64);
            int i3 = __shfl(idx, 3, 64);
            if (lane < 3) {
                int pa = (lane == 2) ? i2 : i1;
                int pb = (lane == 0) ? i2 : i3;
                intra_before[s * 6 + 3 + lane] = pair_dist_d(cb[pa], cb[pb]);
            }
        }
    }
}

// ---------------------------------------------------------------- rf_after assembly + adf
__global__ __launch_bounds__(64) void assemble_kernel(
        const float4* __restrict__ ca, const float4* __restrict__ cb,
        const int* __restrict__ ni_i, const float* __restrict__ intra_after,
        const int* __restrict__ a_before, const float* __restrict__ intra_before,
        const int* __restrict__ sidx,
        float* __restrict__ out_rf, float* __restrict__ adf) {
    __shared__ int s_ni[16];
    __shared__ float s_rf[16 * 28];
    __shared__ float s_ia[6];
    int s = blockIdx.x;
    int t = threadIdx.x;
    if (t < 16) s_ni[t] = ni_i[s * 16 + t];
    if (t < 6) s_ia[t] = intra_after[s * 6 + t];
    __syncthreads();

    // inter block of rf: rf[s,k,12+p*4+q] = D_after(ni[s,p], ni[ni[s,k],q])
    int k = t >> 2, qq = t & 3;
    int nai_q = ni_i[s_ni[k] * 16 + qq];
    float4 pq = ca[nai_q];
#pragma unroll
    for (int p = 0; p < 4; ++p) {
        float4 pp = ca[s_ni[p]];
        s_rf[k * 28 + 12 + p * 4 + qq] = pair_dist_d(pp, pq);
    }
    // center intra (ch 0..5) + neighbor intra (ch 6..11)
    for (int idx = t; idx < 16 * 12; idx += 64) {
        int kk = idx / 12, c = idx % 12;
        float v = (c < 6) ? s_ia[c] : intra_after[s_ni[kk] * 6 + (c - 6)];
        s_rf[kk * 28 + c] = v;
    }
    // adf: [intra_before(6), intra_after(6), inter(16)]
    if (t < 16) {
        int p = t >> 2, q2 = t & 3;
        int ib = a_before[s * 4 + p];
        int ia = sidx[s_ni[q2]];
        adf[s * 28 + 12 + t] = pair_dist_d(cb[ib], cb[ia]);
    } else if (t >= 32 && t < 38) {
        adf[s * 28 + (t - 32)] = intra_before[s * 6 + (t - 32)];
    } else if (t >= 40 && t < 46) {
        adf[s * 28 + 6 + (t - 40)] = s_ia[t - 40];
    }
    __syncthreads();
    const int base = s * 16 * 28;
    for (int idx = t; idx < 16 * 28; idx += 64) out_rf[base + idx] = s_rf[idx];
}

// ---------------------------------------------------------------- mlp1: y_w,y_b = adf@W + b  (stored [C][S])
__global__ __launch_bounds__(256) void mlp1_kernel(
        const float* __restrict__ adf,
        const float* __restrict__ Ww, const float* __restrict__ bw,
        const float* __restrict__ Wb, const float* __restrict__ bb,
        float* __restrict__ y_w, float* __restrict__ y_b) {
    __shared__ float sW[28 * 64], sB[28 * 64];
    int t = threadIdx.x;
    for (int i = t; i < 28 * 64; i += 256) { sW[i] = Ww[i]; sB[i] = Wb[i]; }
    __syncthreads();
    int s = blockIdx.x * 256 + t;
    float a[28];
#pragma unroll
    for (int k2 = 0; k2 < 28; ++k2) a[k2] = adf[s * 28 + k2];
    for (int c = 0; c < 64; ++c) {
        float aw = bw[c], ab = bb[c];
#pragma unroll
        for (int k2 = 0; k2 < 28; ++k2) {
            aw = fmaf(a[k2], sW[k2 * 64 + c], aw);
            ab = fmaf(a[k2], sB[k2 * 64 + c], ab);
        }
        y_w[c * 4096 + s] = aw;
        y_b[c * 4096 + s] = ab;
    }
}

// ---------------------------------------------------------------- batchnorm stats: block per channel
__global__ __launch_bounds__(256) void stats_kernel(
        const float* __restrict__ y,  // [C][4096]
        const float* __restrict__ g0, const float* __restrict__ be0,
        const float* __restrict__ g1, const float* __restrict__ be1, int csplit,
        float* __restrict__ scale, float* __restrict__ shift) {
    int c = blockIdx.x;
    const float* p = y + c * 4096;
    float s1 = 0.0f, s2 = 0.0f;
    for (int i = threadIdx.x; i < 4096; i += 256) {
        float v = p[i];
        s1 += v;
        s2 = fmaf(v, v, s2);
    }
    __shared__ float l1[256], l2[256];
    l1[threadIdx.x] = s1;
    l2[threadIdx.x] = s2;
    __syncthreads();
    for (int off = 128; off; off >>= 1) {
        if (threadIdx.x < off) {
            l1[threadIdx.x] += l1[threadIdx.x + off];
            l2[threadIdx.x] += l2[threadIdx.x + off];
        }
        __syncthreads();
    }
    if (threadIdx.x == 0) {
        float mean = l1[0] * (1.0f / 4096.0f);
        float var = l2[0] * (1.0f / 4096.0f) - mean * mean;
        float g = (c < csplit) ? g0[c] : g1[c - csplit];
        float be = (c < csplit) ? be0[c] : be1[c - csplit];
        float sc = g / sqrtf(var + 1e-5f);
        scale[c] = sc;
        shift[c] = be - mean * sc;
    }
}

// ---------------------------------------------------------------- mlp2: f1 = lrelu(feat*w + b); y_o = [f1,adf]@Wo + bo
// 16 rows per block, cooperative LDS staging, 8 output cols per thread.
__global__ __launch_bounds__(256) void mlp2_kernel(
        const float* __restrict__ y_wb,
        const float* __restrict__ scale1, const float* __restrict__ shift1,
        const float* __restrict__ feature, const int* __restrict__ sidx,
        const float* __restrict__ adf,
        const float* __restrict__ Wo, const float* __restrict__ bo,
        float* __restrict__ y_o) {
    __shared__ float sW[92 * 128];       // 47104 B
    __shared__ float t2[16 * 129];       // padded: bank-conflict-free staging
    __shared__ float scat[16 * 92];      // cat rows
    int t = threadIdx.x;
    int s0 = blockIdx.x * 16;
    for (int i = t; i < 92 * 128; i += 256) sW[i] = Wo[i];
    // B1: t2[row][c] = y_wb[c][s0+row]*scale1[c]+shift1[c]  (c in 0..127)
    for (int i = t; i < 16 * 128; i += 256) {
        int row = i & 15, c = i >> 4;
        t2[row * 129 + c] = fmaf(y_wb[c * 4096 + s0 + row], scale1[c], shift1[c]);
    }
    __syncthreads();
    // B2: cat[0..63] = lrelu(feature*w + b), coalesced feature reads
    for (int rr = 0; rr < 16; rr += 4) {
        int r = rr + (t >> 6);
        int c = t & 63;
        int si = sidx[s0 + r];
        float f = feature[si * 64 + c];
        float v = fmaf(f, t2[r * 129 + c], t2[r * 129 + 64 + c]);
        scat[r * 92 + c] = v >= 0.0f ? v : 0.2f * v;
    }
    // B3: cat[64..91] = adf
    for (int i = t; i < 16 * 28; i += 256) {
        int row = i / 28, k = i % 28;
        scat[row * 92 + 64 + k] = adf[(s0 + row) * 28 + k];
    }
    __syncthreads();
    // C: each thread computes 8 output cols for its row
    int r = t >> 4, cg = t & 15;
    float acc[8];
#pragma unroll
    for (int j = 0; j < 8; ++j) acc[j] = bo[cg * 8 + j];
    for (int c = 0; c < 92; ++c) {
        float a = scat[r * 92 + c];
#pragma unroll
        for (int j = 0; j < 8; ++j)
            acc[j] = fmaf(a, sW[c * 128 + cg * 8 + j], acc[j]);
    }
    int s = s0 + r;
#pragma unroll
    for (int j = 0; j < 8; ++j) y_o[(cg * 8 + j) * 4096 + s] = acc[j];
}

// ---------------------------------------------------------------- final: normalize + lrelu, write feat
__global__ __launch_bounds__(256) void final_kernel(
        const float* __restrict__ y_o,
        const float* __restrict__ scale, const float* __restrict__ shift,
        float* __restrict__ out_feat) {
    int tid = blockIdx.x * 256 + threadIdx.x;  // 0..524287
    int j = tid >> 12;
    int s = tid & 4095;
    float v = fmaf(y_o[tid], scale[j], shift[j]);
    v = v >= 0.0f ? v : 0.2f * v;
    out_feat[s * 128 + j] = v;
}

// ----------------------------------------------------------------
extern "C" void kernel_launch(void* const* d_in, const int* in_sizes, int n_in,
                              void* d_out, int out_size, void* d_ws, size_t ws_size,
                              hipStream_t stream) {
    const float* xyz = (const float*)d_in[0];
    const float* feature = (const float*)d_in[1];
    const int* sidx = (const int*)d_in[2];
    const float* Ww = (const float*)d_in[3];
    const float* bw = (const float*)d_in[4];
    const float* gw = (const float*)d_in[5];
    const float* betaw = (const float*)d_in[6];
    const float* Wb = (const float*)d_in[7];
    const float* bb = (const float*)d_in[8];
    const float* gb = (const float*)d_in[9];
    const float* betab = (const float*)d_in[10];
    const float* Wo = (const float*)d_in[11];
    const float* bo = (const float*)d_in[12];
    const float* go = (const float*)d_in[13];
    const float* betao = (const float*)d_in[14];

    float* out = (float*)d_out;
    float* out_xyz = out;                                  // 4096*3
    float* out_feat = out + 12288;                         // 4096*128
    float* out_rf = out + 12288 + 524288;                  // 4096*16*28
    float* out_ni = out + 12288 + 524288 + 1835008;        // 4096*16

    float* ws = (float*)d_ws;
    float4* cb = (float4*)ws;                  // 8192 float4
    float4* ca = (float4*)(ws + 32768);        // 4096 float4
    int* a_before = (int*)(ws + 49152);        // 4096*4
    float* intra_before = ws + 65536;          // 4096*6
    int* ni_i = (int*)(ws + 90112);            // 4096*16
    float* intra_after = ws + 155648;          // 4096*6
    float* adf = ws + 180224;                  // 4096*28
    float* y_wb = ws + 294912;                 // 128*4096 (y_w then y_b)
    float* y_o = ws + 819200;                  // 128*4096
    float* scale1 = ws + 1343488;              // 128
    float* shift1 = ws + 1343616;              // 128
    float* scale_o = ws + 1343744;             // 128
    float* shift_o = ws + 1343872;             // 128

    stage_kernel<<<32, 256, 0, stream>>>(xyz, sidx, cb, ca, out_xyz);
    knn_kernel<<<2 * S_PTS, 256, 0, stream>>>(cb, ca, sidx, a_before, intra_before,
                                              ni_i, intra_after, out_ni);
    assemble_kernel<<<4096, 64, 0, stream>>>(ca, cb, ni_i, intra_after, a_before,
                                             intra_before, sidx, out_rf, adf);
    mlp1_kernel<<<16, 256, 0, stream>>>(adf, Ww, bw, Wb, bb, y_wb, y_wb + 64 * 4096);
    stats_kernel<<<128, 256, 0, stream>>>(y_wb, gw, betaw, gb, betab, 64, scale1, shift1);
    mlp2_kernel<<<256, 256, 0, stream>>>(y_wb, scale1, shift1, feature, sidx, adf, Wo, bo, y_o);
    stats_kernel<<<128, 256, 0, stream>>>(y_o, go, betao, go, betao, 128, scale_o, shift_o);
    final_kernel<<<2048, 256, 0, stream>>>(y_o, scale_o, shift_o, out_feat);
}

// Round 8
// 237.577 us; speedup vs baseline: 1.3349x; 1.0976x over previous
//
#include <hip/hip_runtime.h>
#include <hip/hip_bf16.h>
#include <math.h>

#define N_PTS 8192
#define S_PTS 4096

// Double-precision pair distance, rounded to float (accurate output values).
__device__ __forceinline__ float pair_dist_d(const float4 a, const float4 b) {
    double ax = a.x, ay = a.y, az = a.z;
    double bx = b.x, by = b.y, bz = b.z;
    double dx = ax - bx, dy = ay - by, dz = az - bz;
    double d2 = dx * dx + dy * dy + dz * dz;
    return d2 > 0.0 ? (float)sqrt(d2) : 0.0f;
}

// Strict fp32 gram-formula d^2 (bit-identical to the reference cdist pipeline).
__device__ __forceinline__ float d2_f32_gram(const float4 a, const float4 b) {
    float dot = __fadd_rn(__fadd_rn(__fmul_rn(a.x, b.x), __fmul_rn(a.y, b.y)),
                          __fmul_rn(a.z, b.z));
    float d2 = __fsub_rn(__fadd_rn(a.w, b.w), __fmul_rn(2.0f, dot));
    return fmaxf(d2, 0.0f);
}

// ---------------------------------------------------------------- stage
__global__ __launch_bounds__(256) void stage_kernel(
        const float* __restrict__ xyz, const int* __restrict__ sidx,
        float4* __restrict__ cb, float4* __restrict__ ca,
        float* __restrict__ out_xyz_s) {
    int i = blockIdx.x * blockDim.x + threadIdx.x;
    if (i < N_PTS) {
        float x = xyz[i * 3 + 0], y = xyz[i * 3 + 1], z = xyz[i * 3 + 2];
        float sq = __fadd_rn(__fadd_rn(__fmul_rn(x, x), __fmul_rn(y, y)),
                             __fmul_rn(z, z));
        cb[i] = make_float4(x, y, z, sq);
    }
    if (i < S_PTS) {
        int si = sidx[i];
        float x = xyz[si * 3 + 0], y = xyz[si * 3 + 1], z = xyz[si * 3 + 2];
        float sq = __fadd_rn(__fadd_rn(__fmul_rn(x, x), __fmul_rn(y, y)),
                             __fmul_rn(z, z));
        ca[i] = make_float4(x, y, z, sq);
        out_xyz_s[i * 3 + 0] = x;
        out_xyz_s[i * 3 + 1] = y;
        out_xyz_s[i * 3 + 2] = z;
    }
}

// ---------------------------------------------------------------- knn: histogram select
// One 256-thread block per query. Selection on d^2-bin histogram; final exact
// order by (fp32 D, idx) u64 keys — identical semantics to the proven ladder:
// rank by fp32-gram D, ties (incl. d2<=0 collapse set) toward lower index.
// Bin = float_bits(d2) >> 20 (exp + 3 mantissa bits). Collecting bins <= B+1
// covers all fp32-sqrt D-tie partners (within ~2 d2-ulps << bin width).
template <int J, int K>
__device__ __forceinline__ unsigned long long knn_hist_select(
        const float4 q, const float4* __restrict__ cand,
        unsigned* hist, unsigned long long* buf, unsigned* meta, int t) {
    int lane = t & 63, wid = t >> 6;
    for (int i = t; i < 2048; i += 256) hist[i] = 0;
    if (t == 0) meta[0] = 0;
    __syncthreads();
    // pass 1: histogram of d2 bins
#pragma unroll
    for (int j = 0; j < J; ++j) {
        float d2 = d2_f32_gram(q, cand[t + 256 * j]);
        unsigned bin = __float_as_uint(d2) >> 20;
        bin = bin > 2047u ? 2047u : bin;
        atomicAdd(&hist[bin], 1u);
    }
    __syncthreads();
    // find crossing bin B (cumulative count reaches K)
    unsigned cnts[8], part = 0;
#pragma unroll
    for (int b = 0; b < 8; ++b) { cnts[b] = hist[8 * t + b]; part += cnts[b]; }
    unsigned x = part;
    for (int off = 1; off < 64; off <<= 1) {
        unsigned y = __shfl_up(x, off, 64);
        if (lane >= off) x += y;
    }
    if (lane == 63) meta[2 + wid] = x;
    __syncthreads();
    unsigned base = x - part;
    for (int w = 0; w < wid; ++w) base += meta[2 + w];
    unsigned cum = base;
#pragma unroll
    for (int b = 0; b < 8; ++b) {
        unsigned nc = cum + cnts[b];
        if (cum < K && nc >= K) meta[1] = (unsigned)(8 * t + b);  // unique writer
        cum = nc;
    }
    __syncthreads();
    unsigned B = meta[1];
    // pass 2: collect candidates with bin <= B+1
#pragma unroll
    for (int j = 0; j < J; ++j) {
        float d2 = d2_f32_gram(q, cand[t + 256 * j]);
        unsigned bin = __float_as_uint(d2) >> 20;
        bin = bin > 2047u ? 2047u : bin;
        if (bin <= B + 1) {
            unsigned pos = atomicAdd(&meta[0], 1u);
            if (pos < 192u) {
                float D = d2 > 0.0f ? __fsqrt_rn(d2) : 0.0f;
                buf[pos] = ((unsigned long long)__float_as_uint(D) << 32) |
                           (unsigned long long)(unsigned)(t + 256 * j);
            }
        }
    }
    __syncthreads();
    unsigned cnt = meta[0];
    unsigned long long res = ~0ull;
    if (wid == 0) {
        if (cnt <= 64u) {
            unsigned long long v = (lane < (int)cnt) ? buf[lane] : ~0ull;
            // bitonic sort 64 across lanes, ascending
#pragma unroll
            for (int k = 2; k <= 64; k <<= 1) {
#pragma unroll
                for (int j2 = k >> 1; j2 >= 1; j2 >>= 1) {
                    unsigned long long o = __shfl_xor(v, j2, 64);
                    bool keepMin = (((lane & j2) == 0) == ((lane & k) == 0));
                    bool less = o < v;
                    v = keepMin ? (less ? o : v) : (less ? v : o);
                }
            }
            res = v;  // lane r holds rank r
        } else {
            // rare fallback: per-lane sorted-3 + K-round extract (cnt <= 192)
            unsigned long long L0 = ~0ull, L1 = ~0ull, L2 = ~0ull;
            unsigned cc = cnt > 192u ? 192u : cnt;
            for (unsigned m = lane; m < cc; m += 64) {
                unsigned long long kk = buf[m];
                if (kk < L2) {
                    if (kk < L1) {
                        L2 = L1;
                        if (kk < L0) { L1 = L0; L0 = kk; } else L1 = kk;
                    } else L2 = kk;
                }
            }
#pragma unroll
            for (int r = 0; r < K; ++r) {
                unsigned long long m = L0;
#pragma unroll
                for (int off = 32; off >= 1; off >>= 1) {
                    unsigned long long o = __shfl_xor(m, off, 64);
                    m = (o < m) ? o : m;
                }
                if (lane == r) res = m;
                if (L0 == m) { L0 = L1; L1 = L2; L2 = ~0ull; }
            }
        }
    }
    return res;
}

// blocks [0, S_PTS): "after" queries (top-16 over ca, 4096 cands)
// blocks [S_PTS, 2*S_PTS): "before" queries (top-4 over cb, 8192 cands)
__global__ __launch_bounds__(256, 4) void knn_kernel(
        const float4* __restrict__ cb, const float4* __restrict__ ca,
        const int* __restrict__ sidx,
        int* __restrict__ a_before, float* __restrict__ intra_before,
        int* __restrict__ ni_i, float* __restrict__ intra_after,
        float* __restrict__ out_ni) {
    __shared__ unsigned hist[2048];
    __shared__ unsigned long long buf[192];
    __shared__ unsigned meta[8];
    int t = threadIdx.x, lane = t & 63, wid = t >> 6;
    int bid = blockIdx.x;
    if (bid < S_PTS) {
        int s = bid;
        float4 q = ca[s];
        unsigned long long res = knn_hist_select<16, 16>(q, ca, hist, buf, meta, t);
        if (wid == 0) {
            int idx = (int)(res & 0xffffffffull);
            if (lane < 16) {
                ni_i[s * 16 + lane] = idx;
                out_ni[s * 16 + lane] = (float)idx;
            }
            if (lane >= 1 && lane < 4)
                intra_after[s * 6 + (lane - 1)] = pair_dist_d(q, ca[idx]);
            int i1 = __shfl(idx, 1, 64);
            int i2 = __shfl(idx, 2, 64);
            int i3 = __shfl(idx, 3, 64);
            if (lane < 3) {  // pairs (1,2),(1,3),(2,3)
                int pa = (lane == 2) ? i2 : i1;
                int pb = (lane == 0) ? i2 : i3;
                intra_after[s * 6 + 3 + lane] = pair_dist_d(ca[pa], ca[pb]);
            }
        }
    } else {
        int s = bid - S_PTS;
        float4 q = cb[sidx[s]];
        unsigned long long res = knn_hist_select<32, 4>(q, cb, hist, buf, meta, t);
        if (wid == 0) {
            int idx = (int)(res & 0xffffffffull);
            if (lane < 4) a_before[s * 4 + lane] = idx;
            if (lane >= 1 && lane < 4)
                intra_before[s * 6 + (lane - 1)] = pair_dist_d(q, cb[idx]);
            int i1 = __shfl(idx, 1, 64);
            int i2 = __shfl(idx, 2, 64);
            int i3 = __shfl(idx, 3, 64);
            if (lane < 3) {
                int pa = (lane == 2) ? i2 : i1;
                int pb = (lane == 0) ? i2 : i3;
                intra_before[s * 6 + 3 + lane] = pair_dist_d(cb[pa], cb[pb]);
            }
        }
    }
}

// ---------------------------------------------------------------- rf_after assembly + adf
__global__ __launch_bounds__(64) void assemble_kernel(
        const float4* __restrict__ ca, const float4* __restrict__ cb,
        const int* __restrict__ ni_i, const float* __restrict__ intra_after,
        const int* __restrict__ a_before, const float* __restrict__ intra_before,
        const int* __restrict__ sidx,
        float* __restrict__ out_rf, float* __restrict__ adf) {
    __shared__ int s_ni[16];
    __shared__ float s_rf[16 * 28];
    __shared__ float s_ia[6];
    int s = blockIdx.x;
    int t = threadIdx.x;
    if (t < 16) s_ni[t] = ni_i[s * 16 + t];
    if (t < 6) s_ia[t] = intra_after[s * 6 + t];
    __syncthreads();

    // inter block of rf: rf[s,k,12+p*4+q] = D_after(ni[s,p], ni[ni[s,k],q])
    int k = t >> 2, qq = t & 3;
    int nai_q = ni_i[s_ni[k] * 16 + qq];
    float4 pq = ca[nai_q];
#pragma unroll
    for (int p = 0; p < 4; ++p) {
        float4 pp = ca[s_ni[p]];
        s_rf[k * 28 + 12 + p * 4 + qq] = pair_dist_d(pp, pq);
    }
    // center intra (ch 0..5) + neighbor intra (ch 6..11)
    for (int idx = t; idx < 16 * 12; idx += 64) {
        int kk = idx / 12, c = idx % 12;
        float v = (c < 6) ? s_ia[c] : intra_after[s_ni[kk] * 6 + (c - 6)];
        s_rf[kk * 28 + c] = v;
    }
    // adf: [intra_before(6), intra_after(6), inter(16)]
    if (t < 16) {
        int p = t >> 2, q2 = t & 3;
        int ib = a_before[s * 4 + p];
        int ia = sidx[s_ni[q2]];
        adf[s * 28 + 12 + t] = pair_dist_d(cb[ib], cb[ia]);
    } else if (t >= 32 && t < 38) {
        adf[s * 28 + (t - 32)] = intra_before[s * 6 + (t - 32)];
    } else if (t >= 40 && t < 46) {
        adf[s * 28 + 6 + (t - 40)] = s_ia[t - 40];
    }
    __syncthreads();
    const int base = s * 16 * 28;
    for (int idx = t; idx < 16 * 28; idx += 64) out_rf[base + idx] = s_rf[idx];
}

// ---------------------------------------------------------------- mlp1: y_w,y_b = adf@W + b  (stored [C][S])
__global__ __launch_bounds__(256) void mlp1_kernel(
        const float* __restrict__ adf,
        const float* __restrict__ Ww, const float* __restrict__ bw,
        const float* __restrict__ Wb, const float* __restrict__ bb,
        float* __restrict__ y_w, float* __restrict__ y_b) {
    __shared__ float sW[28 * 64], sB[28 * 64];
    int t = threadIdx.x;
    for (int i = t; i < 28 * 64; i += 256) { sW[i] = Ww[i]; sB[i] = Wb[i]; }
    __syncthreads();
    int s = blockIdx.x * 256 + t;
    float a[28];
#pragma unroll
    for (int k2 = 0; k2 < 28; ++k2) a[k2] = adf[s * 28 + k2];
    for (int c = 0; c < 64; ++c) {
        float aw = bw[c], ab = bb[c];
#pragma unroll
        for (int k2 = 0; k2 < 28; ++k2) {
            aw = fmaf(a[k2], sW[k2 * 64 + c], aw);
            ab = fmaf(a[k2], sB[k2 * 64 + c], ab);
        }
        y_w[c * 4096 + s] = aw;
        y_b[c * 4096 + s] = ab;
    }
}

// ---------------------------------------------------------------- batchnorm stats: block per channel
__global__ __launch_bounds__(256) void stats_kernel(
        const float* __restrict__ y,  // [C][4096]
        const float* __restrict__ g0, const float* __restrict__ be0,
        const float* __restrict__ g1, const float* __restrict__ be1, int csplit,
        float* __restrict__ scale, float* __restrict__ shift) {
    int c = blockIdx.x;
    const float* p = y + c * 4096;
    float s1 = 0.0f, s2 = 0.0f;
    for (int i = threadIdx.x; i < 4096; i += 256) {
        float v = p[i];
        s1 += v;
        s2 = fmaf(v, v, s2);
    }
    __shared__ float l1[256], l2[256];
    l1[threadIdx.x] = s1;
    l2[threadIdx.x] = s2;
    __syncthreads();
    for (int off = 128; off; off >>= 1) {
        if (threadIdx.x < off) {
            l1[threadIdx.x] += l1[threadIdx.x + off];
            l2[threadIdx.x] += l2[threadIdx.x + off];
        }
        __syncthreads();
    }
    if (threadIdx.x == 0) {
        float mean = l1[0] * (1.0f / 4096.0f);
        float var = l2[0] * (1.0f / 4096.0f) - mean * mean;
        float g = (c < csplit) ? g0[c] : g1[c - csplit];
        float be = (c < csplit) ? be0[c] : be1[c - csplit];
        float sc = g / sqrtf(var + 1e-5f);
        scale[c] = sc;
        shift[c] = be - mean * sc;
    }
}

// ---------------------------------------------------------------- mlp2: f1 = lrelu(feat*w + b); y_o = [f1,adf]@Wo + bo
__global__ __launch_bounds__(256) void mlp2_kernel(
        const float* __restrict__ y_wb,
        const float* __restrict__ scale1, const float* __restrict__ shift1,
        const float* __restrict__ feature, const int* __restrict__ sidx,
        const float* __restrict__ adf,
        const float* __restrict__ Wo, const float* __restrict__ bo,
        float* __restrict__ y_o) {
    __shared__ float sW[92 * 128];       // 47104 B
    __shared__ float t2[16 * 129];       // padded staging
    __shared__ float scat[16 * 92];      // cat rows
    int t = threadIdx.x;
    int s0 = blockIdx.x * 16;
    for (int i = t; i < 92 * 128; i += 256) sW[i] = Wo[i];
    for (int i = t; i < 16 * 128; i += 256) {
        int row = i & 15, c = i >> 4;
        t2[row * 129 + c] = fmaf(y_wb[c * 4096 + s0 + row], scale1[c], shift1[c]);
    }
    __syncthreads();
    for (int rr = 0; rr < 16; rr += 4) {
        int r = rr + (t >> 6);
        int c = t & 63;
        int si = sidx[s0 + r];
        float f = feature[si * 64 + c];
        float v = fmaf(f, t2[r * 129 + c], t2[r * 129 + 64 + c]);
        scat[r * 92 + c] = v >= 0.0f ? v : 0.2f * v;
    }
    for (int i = t; i < 16 * 28; i += 256) {
        int row = i / 28, k = i % 28;
        scat[row * 92 + 64 + k] = adf[(s0 + row) * 28 + k];
    }
    __syncthreads();
    int r = t >> 4, cg = t & 15;
    float acc[8];
#pragma unroll
    for (int j = 0; j < 8; ++j) acc[j] = bo[cg * 8 + j];
    for (int c = 0; c < 92; ++c) {
        float a = scat[r * 92 + c];
#pragma unroll
        for (int j = 0; j < 8; ++j)
            acc[j] = fmaf(a, sW[c * 128 + cg * 8 + j], acc[j]);
    }
    int s = s0 + r;
#pragma unroll
    for (int j = 0; j < 8; ++j) y_o[(cg * 8 + j) * 4096 + s] = acc[j];
}

// ---------------------------------------------------------------- final: normalize + lrelu, write feat
__global__ __launch_bounds__(256) void final_kernel(
        const float* __restrict__ y_o,
        const float* __restrict__ scale, const float* __restrict__ shift,
        float* __restrict__ out_feat) {
    int tid = blockIdx.x * 256 + threadIdx.x;  // 0..524287
    int j = tid >> 12;
    int s = tid & 4095;
    float v = fmaf(y_o[tid], scale[j], shift[j]);
    v = v >= 0.0f ? v : 0.2f * v;
    out_feat[s * 128 + j] = v;
}

// ----------------------------------------------------------------
extern "C" void kernel_launch(void* const* d_in, const int* in_sizes, int n_in,
                              void* d_out, int out_size, void* d_ws, size_t ws_size,
                              hipStream_t stream) {
    const float* xyz = (const float*)d_in[0];
    const float* feature = (const float*)d_in[1];
    const int* sidx = (const int*)d_in[2];
    const float* Ww = (const float*)d_in[3];
    const float* bw = (const float*)d_in[4];
    const float* gw = (const float*)d_in[5];
    const float* betaw = (const float*)d_in[6];
    const float* Wb = (const float*)d_in[7];
    const float* bb = (const float*)d_in[8];
    const float* gb = (const float*)d_in[9];
    const float* betab = (const float*)d_in[10];
    const float* Wo = (const float*)d_in[11];
    const float* bo = (const float*)d_in[12];
    const float* go = (const float*)d_in[13];
    const float* betao = (const float*)d_in[14];

    float* out = (float*)d_out;
    float* out_xyz = out;                                  // 4096*3
    float* out_feat = out + 12288;                         // 4096*128
    float* out_rf = out + 12288 + 524288;                  // 4096*16*28
    float* out_ni = out + 12288 + 524288 + 1835008;        // 4096*16

    float* ws = (float*)d_ws;
    float4* cb = (float4*)ws;                  // 8192 float4
    float4* ca = (float4*)(ws + 32768);        // 4096 float4
    int* a_before = (int*)(ws + 49152);        // 4096*4
    float* intra_before = ws + 65536;          // 4096*6
    int* ni_i = (int*)(ws + 90112);            // 4096*16
    float* intra_after = ws + 155648;          // 4096*6
    float* adf = ws + 180224;                  // 4096*28
    float* y_wb = ws + 294912;                 // 128*4096 (y_w then y_b)
    float* y_o = ws + 819200;                  // 128*4096
    float* scale1 = ws + 1343488;              // 128
    float* shift1 = ws + 1343616;              // 128
    float* scale_o = ws + 1343744;             // 128
    float* shift_o = ws + 1343872;             // 128

    stage_kernel<<<32, 256, 0, stream>>>(xyz, sidx, cb, ca, out_xyz);
    knn_kernel<<<2 * S_PTS, 256, 0, stream>>>(cb, ca, sidx, a_before, intra_before,
                                              ni_i, intra_after, out_ni);
    assemble_kernel<<<4096, 64, 0, stream>>>(ca, cb, ni_i, intra_after, a_before,
                                             intra_before, sidx, out_rf, adf);
    mlp1_kernel<<<16, 256, 0, stream>>>(adf, Ww, bw, Wb, bb, y_wb, y_wb + 64 * 4096);
    stats_kernel<<<128, 256, 0, stream>>>(y_wb, gw, betaw, gb, betab, 64, scale1, shift1);
    mlp2_kernel<<<256, 256, 0, stream>>>(y_wb, scale1, shift1, feature, sidx, adf, Wo, bo, y_o);
    stats_kernel<<<128, 256, 0, stream>>>(y_o, go, betao, go, betao, 128, scale_o, shift_o);
    final_kernel<<<2048, 256, 0, stream>>>(y_o, scale_o, shift_o, out_feat);
}

// Round 9
// 171.457 us; speedup vs baseline: 1.8497x; 1.3856x over previous
//
#include <hip/hip_runtime.h>
#include <hip/hip_bf16.h>
#include <math.h>

#define N_PTS 8192
#define S_PTS 4096
typedef unsigned long long u64;
typedef unsigned u32;

// Double-precision pair distance, rounded to float (accurate output values).
__device__ __forceinline__ float pair_dist_d(const float4 a, const float4 b) {
    double ax = a.x, ay = a.y, az = a.z;
    double bx = b.x, by = b.y, bz = b.z;
    double dx = ax - bx, dy = ay - by, dz = az - bz;
    double d2 = dx * dx + dy * dy + dz * dz;
    return d2 > 0.0 ? (float)sqrt(d2) : 0.0f;
}

// Strict fp32 gram-formula d^2 (bit-identical to the reference cdist pipeline).
__device__ __forceinline__ float d2_f32_gram(const float4 a, const float4 b) {
    float dot = __fadd_rn(__fadd_rn(__fmul_rn(a.x, b.x), __fmul_rn(a.y, b.y)),
                          __fmul_rn(a.z, b.z));
    float d2 = __fsub_rn(__fadd_rn(a.w, b.w), __fmul_rn(2.0f, dot));
    return fmaxf(d2, 0.0f);
}

// ---------------------------------------------------------------- stage
__global__ __launch_bounds__(256) void stage_kernel(
        const float* __restrict__ xyz, const int* __restrict__ sidx,
        float4* __restrict__ cb, float4* __restrict__ ca,
        float* __restrict__ out_xyz_s) {
    int i = blockIdx.x * blockDim.x + threadIdx.x;
    if (i < N_PTS) {
        float x = xyz[i * 3 + 0], y = xyz[i * 3 + 1], z = xyz[i * 3 + 2];
        float sq = __fadd_rn(__fadd_rn(__fmul_rn(x, x), __fmul_rn(y, y)),
                             __fmul_rn(z, z));
        cb[i] = make_float4(x, y, z, sq);
    }
    if (i < S_PTS) {
        int si = sidx[i];
        float x = xyz[si * 3 + 0], y = xyz[si * 3 + 1], z = xyz[si * 3 + 2];
        float sq = __fadd_rn(__fadd_rn(__fmul_rn(x, x), __fmul_rn(y, y)),
                             __fmul_rn(z, z));
        ca[i] = make_float4(x, y, z, sq);
        out_xyz_s[i * 3 + 0] = x;
        out_xyz_s[i * 3 + 1] = y;
        out_xyz_s[i * 3 + 2] = z;
    }
}

// ---------------------------------------------------------------- knn select
// Exact top-K by (fp32-gram D, idx) — same semantics as validated rounds.
// Threshold: tau = K-th smallest of 64 lane-minima (provable upper bound on
// the true K-th smallest). Collect d2<=tau (cnt>=K guaranteed), sort.
// No LDS atomics, no data-dependent ladders in the main path.

// full single-wave ladder (ultra-rare fallback), wave0 only
template <int KOUT, int ITERS>
__device__ u64 knn_full_ladder(const float4 q, const float4* __restrict__ cand,
                               int lane) {
    u32 Lk[KOUT], Li[KOUT];
#pragma unroll
    for (int j = 0; j < KOUT; ++j) { Lk[j] = 0xFFFFFFFFu; Li[j] = 0xFFFFFFFFu; }
    int c = lane;
    for (int tt = 0; tt < ITERS; ++tt, c += 64) {
        float d2 = d2_f32_gram(q, cand[c]);
        float Df = d2 > 0.0f ? __fsqrt_rn(d2) : 0.0f;
        u32 kb = __float_as_uint(Df);
        if (kb < Lk[KOUT - 1]) {
#pragma unroll
            for (int j = KOUT - 1; j >= 1; --j) {
                bool up = kb < Lk[j - 1], ins = kb < Lk[j];
                Lk[j] = up ? Lk[j - 1] : (ins ? kb : Lk[j]);
                Li[j] = up ? Li[j - 1] : (ins ? (u32)c : Li[j]);
            }
            bool i0 = kb < Lk[0];
            Lk[0] = i0 ? kb : Lk[0];
            Li[0] = i0 ? (u32)c : Li[0];
        }
    }
    u64 Lu[KOUT];
#pragma unroll
    for (int j = 0; j < KOUT; ++j) Lu[j] = ((u64)Lk[j] << 32) | (u64)Li[j];
    u64 res = ~0ull;
#pragma unroll
    for (int r = 0; r < KOUT; ++r) {
        u64 m = Lu[0];
#pragma unroll
        for (int off = 32; off >= 1; off >>= 1) {
            u64 o = __shfl_xor(m, off, 64);
            m = (o < m) ? o : m;
        }
        if (lane == r) res = m;
        if (Lu[0] == m) {
#pragma unroll
            for (int j = 0; j < KOUT - 1; ++j) Lu[j] = Lu[j + 1];
            Lu[KOUT - 1] = ~0ull;
        }
    }
    return res;
}

template <int J, int K, int NC>
__device__ u64 knn_select(const float4 q, const float4* __restrict__ cand,
                          int t, u32* mins, u64* buf, u32* shm) {
    int lane = t & 63, wid = t >> 6;
    // pass 1: d^2 bits in registers + per-thread min
    u32 d2b[J];
    u32 m = 0xFFFFFFFFu;
#pragma unroll
    for (int j = 0; j < J; ++j) {
        float d2 = d2_f32_gram(q, cand[t + 256 * j]);
        u32 b = __float_as_uint(d2);
        d2b[j] = b;
        m = b < m ? b : m;
    }
    mins[t] = m;
    __syncthreads();
    // tau = K-th smallest of 64 lane-minima (wave0 bitonic sort64, u32)
    if (wid == 0) {
        u32 v = mins[lane];
        u32 v2 = mins[lane + 64];  v = v2 < v ? v2 : v;
        v2 = mins[lane + 128];     v = v2 < v ? v2 : v;
        v2 = mins[lane + 192];     v = v2 < v ? v2 : v;
#pragma unroll
        for (int k = 2; k <= 64; k <<= 1) {
#pragma unroll
            for (int j2 = k >> 1; j2 >= 1; j2 >>= 1) {
                u32 o = __shfl_xor(v, j2, 64);
                bool keepMin = (((lane & j2) == 0) == ((lane & k) == 0));
                bool less = o < v;
                v = keepMin ? (less ? o : v) : (less ? v : o);
            }
        }
        if (lane == K - 1) shm[0] = v;
    }
    __syncthreads();
    u32 tau = shm[0];
    // pass 2: count qualifying, block prefix scan
    u32 c = 0;
#pragma unroll
    for (int j = 0; j < J; ++j) c += (d2b[j] <= tau) ? 1u : 0u;
    u32 x = c;
#pragma unroll
    for (int off = 1; off < 64; off <<= 1) {
        u32 y = __shfl_up(x, off, 64);
        if (lane >= off) x += y;
    }
    if (lane == 63) shm[1 + wid] = x;
    __syncthreads();
    u32 base = x - c;
    for (int w = 0; w < wid; ++w) base += shm[1 + w];
    u32 cnt = shm[1] + shm[2] + shm[3] + shm[4];
    if (cnt <= 256u) {
        u32 off = base;
#pragma unroll
        for (int j = 0; j < J; ++j) {
            if (d2b[j] <= tau) {
                float d2 = __uint_as_float(d2b[j]);
                float D = d2 > 0.0f ? __fsqrt_rn(d2) : 0.0f;
                buf[off++] = ((u64)__float_as_uint(D) << 32) |
                             (u64)(u32)(t + 256 * j);
            }
        }
    }
    __syncthreads();
    u64 res = ~0ull;
    if (wid == 0) {
        if (cnt <= 64u) {
            u64 v = (lane < (int)cnt) ? buf[lane] : ~0ull;
#pragma unroll
            for (int k = 2; k <= 64; k <<= 1) {
#pragma unroll
                for (int j2 = k >> 1; j2 >= 1; j2 >>= 1) {
                    u64 o = __shfl_xor(v, j2, 64);
                    bool keepMin = (((lane & j2) == 0) == ((lane & k) == 0));
                    bool less = o < v;
                    v = keepMin ? (less ? o : v) : (less ? v : o);
                }
            }
            res = v;  // lane r holds rank r
        } else if (cnt <= 256u) {
            // per-lane sorted-4 (<=4 cands/lane) + K-round extract
            u64 L0 = ~0ull, L1 = ~0ull, L2 = ~0ull, L3 = ~0ull;
            for (u32 mm = lane; mm < cnt; mm += 64) {
                u64 kk = buf[mm];
                if (kk < L3) {
                    if (kk < L1) {
                        L3 = L2; L2 = L1;
                        if (kk < L0) { L1 = L0; L0 = kk; } else L1 = kk;
                    } else {
                        if (kk < L2) { L3 = L2; L2 = kk; } else L3 = kk;
                    }
                }
            }
#pragma unroll
            for (int r = 0; r < K; ++r) {
                u64 mr = L0;
#pragma unroll
                for (int off = 32; off >= 1; off >>= 1) {
                    u64 o = __shfl_xor(mr, off, 64);
                    mr = (o < mr) ? o : mr;
                }
                if (lane == r) res = mr;
                if (L0 == mr) { L0 = L1; L1 = L2; L2 = L3; L3 = ~0ull; }
            }
        } else {
            res = knn_full_ladder<K, NC / 64>(q, cand, lane);
        }
    }
    return res;
}

// blocks [0, S_PTS): "after" (top-16 over ca); [S_PTS, 2S): "before" (top-4 over cb)
__global__ __launch_bounds__(256, 4) void knn_kernel(
        const float4* __restrict__ cb, const float4* __restrict__ ca,
        const int* __restrict__ sidx,
        int* __restrict__ a_before, float* __restrict__ intra_before,
        int* __restrict__ ni_i, float* __restrict__ intra_after,
        float* __restrict__ out_ni) {
    __shared__ u32 mins[256];
    __shared__ u64 buf[256];
    __shared__ u32 shm[8];
    int t = threadIdx.x, lane = t & 63, wid = t >> 6;
    int bid = blockIdx.x;
    if (bid < S_PTS) {
        int s = bid;
        float4 q = ca[s];
        u64 res = knn_select<16, 16, 4096>(q, ca, t, mins, buf, shm);
        if (wid == 0) {
            int idx = (int)(res & 0xffffffffull);
            if (lane < 16) {
                ni_i[s * 16 + lane] = idx;
                out_ni[s * 16 + lane] = (float)idx;
            }
            if (lane >= 1 && lane < 4)
                intra_after[s * 6 + (lane - 1)] = pair_dist_d(q, ca[idx]);
            int i1 = __shfl(idx, 1, 64);
            int i2 = __shfl(idx, 2, 64);
            int i3 = __shfl(idx, 3, 64);
            if (lane < 3) {  // pairs (1,2),(1,3),(2,3)
                int pa = (lane == 2) ? i2 : i1;
                int pb = (lane == 0) ? i2 : i3;
                intra_after[s * 6 + 3 + lane] = pair_dist_d(ca[pa], ca[pb]);
            }
        }
    } else {
        int s = bid - S_PTS;
        float4 q = cb[sidx[s]];
        u64 res = knn_select<32, 4, 8192>(q, cb, t, mins, buf, shm);
        if (wid == 0) {
            int idx = (int)(res & 0xffffffffull);
            if (lane < 4) a_before[s * 4 + lane] = idx;
            if (lane >= 1 && lane < 4)
                intra_before[s * 6 + (lane - 1)] = pair_dist_d(q, cb[idx]);
            int i1 = __shfl(idx, 1, 64);
            int i2 = __shfl(idx, 2, 64);
            int i3 = __shfl(idx, 3, 64);
            if (lane < 3) {
                int pa = (lane == 2) ? i2 : i1;
                int pb = (lane == 0) ? i2 : i3;
                intra_before[s * 6 + 3 + lane] = pair_dist_d(cb[pa], cb[pb]);
            }
        }
    }
}

// ---------------------------------------------------------------- rf_after assembly + adf
// 4 samples per block, one wave each.
__global__ __launch_bounds__(256) void assemble_kernel(
        const float4* __restrict__ ca, const float4* __restrict__ cb,
        const int* __restrict__ ni_i, const float* __restrict__ intra_after,
        const int* __restrict__ a_before, const float* __restrict__ intra_before,
        const int* __restrict__ sidx,
        float* __restrict__ out_rf, float* __restrict__ adf) {
    __shared__ int s_ni[4][16];
    __shared__ float s_rf[4][16 * 28];
    __shared__ float s_ia[4][8];
    int t = threadIdx.x, wid = t >> 6, lane = t & 63;
    int s = blockIdx.x * 4 + wid;
    if (lane < 16) s_ni[wid][lane] = ni_i[s * 16 + lane];
    if (lane < 6) s_ia[wid][lane] = intra_after[s * 6 + lane];
    __syncthreads();

    // inter block of rf: rf[s,k,12+p*4+q] = D_after(ni[s,p], ni[ni[s,k],q])
    int k = lane >> 2, qq = lane & 3;
    int nai_q = ni_i[s_ni[wid][k] * 16 + qq];
    float4 pq = ca[nai_q];
#pragma unroll
    for (int p = 0; p < 4; ++p) {
        float4 pp = ca[s_ni[wid][p]];
        s_rf[wid][k * 28 + 12 + p * 4 + qq] = pair_dist_d(pp, pq);
    }
    // center intra (ch 0..5) + neighbor intra (ch 6..11)
    for (int idx = lane; idx < 16 * 12; idx += 64) {
        int kk = idx / 12, c = idx % 12;
        float v = (c < 6) ? s_ia[wid][c] : intra_after[s_ni[wid][kk] * 6 + (c - 6)];
        s_rf[wid][kk * 28 + c] = v;
    }
    // adf: [intra_before(6), intra_after(6), inter(16)]
    if (lane < 16) {
        int p = lane >> 2, q2 = lane & 3;
        int ib = a_before[s * 4 + p];
        int ia = sidx[s_ni[wid][q2]];
        adf[s * 28 + 12 + lane] = pair_dist_d(cb[ib], cb[ia]);
    } else if (lane >= 32 && lane < 38) {
        adf[s * 28 + (lane - 32)] = intra_before[s * 6 + (lane - 32)];
    } else if (lane >= 40 && lane < 46) {
        adf[s * 28 + 6 + (lane - 40)] = s_ia[wid][lane - 40];
    }
    __syncthreads();
    const int base = s * 16 * 28;
    for (int idx = lane; idx < 16 * 28; idx += 64) out_rf[base + idx] = s_rf[wid][idx];
}

// ---------------------------------------------------------------- mlp1: y_wb[c][s] = adf@[Ww|Wb] + [bw|bb]
// 32 samples per block, 16 output channels per thread, 128 blocks.
__global__ __launch_bounds__(256) void mlp1_kernel(
        const float* __restrict__ adf,
        const float* __restrict__ Ww, const float* __restrict__ bw,
        const float* __restrict__ Wb, const float* __restrict__ bb,
        float* __restrict__ y_wb) {
    __shared__ float sW[28 * 128];   // col c<64: Ww, else Wb
    __shared__ float sb[128];
    __shared__ float sA[32 * 28];
    int t = threadIdx.x;
    for (int i = t; i < 28 * 128; i += 256) {
        int k = i >> 7, c = i & 127;
        sW[i] = (c < 64) ? Ww[k * 64 + c] : Wb[k * 64 + (c - 64)];
    }
    if (t < 128) sb[t] = (t < 64) ? bw[t] : bb[t - 64];
    int s0 = blockIdx.x * 32;
    for (int i = t; i < 32 * 28; i += 256) sA[i] = adf[s0 * 28 + i];
    __syncthreads();
    int sl = t >> 3, grp = t & 7;
    int s = s0 + sl;
    float acc[16];
#pragma unroll
    for (int k = 0; k < 16; ++k) acc[k] = sb[grp * 16 + k];
    for (int k2 = 0; k2 < 28; ++k2) {
        float a = sA[sl * 28 + k2];
#pragma unroll
        for (int k = 0; k < 16; ++k)
            acc[k] = fmaf(a, sW[k2 * 128 + grp * 16 + k], acc[k]);
    }
#pragma unroll
    for (int k = 0; k < 16; ++k) y_wb[(grp * 16 + k) * 4096 + s] = acc[k];
}

// ---------------------------------------------------------------- batchnorm stats: block per channel
__global__ __launch_bounds__(256) void stats_kernel(
        const float* __restrict__ y,  // [C][4096]
        const float* __restrict__ g0, const float* __restrict__ be0,
        const float* __restrict__ g1, const float* __restrict__ be1, int csplit,
        float* __restrict__ scale, float* __restrict__ shift) {
    int c = blockIdx.x;
    const float* p = y + c * 4096;
    float s1 = 0.0f, s2 = 0.0f;
    for (int i = threadIdx.x; i < 4096; i += 256) {
        float v = p[i];
        s1 += v;
        s2 = fmaf(v, v, s2);
    }
    __shared__ float l1[256], l2[256];
    l1[threadIdx.x] = s1;
    l2[threadIdx.x] = s2;
    __syncthreads();
    for (int off = 128; off; off >>= 1) {
        if (threadIdx.x < off) {
            l1[threadIdx.x] += l1[threadIdx.x + off];
            l2[threadIdx.x] += l2[threadIdx.x + off];
        }
        __syncthreads();
    }
    if (threadIdx.x == 0) {
        float mean = l1[0] * (1.0f / 4096.0f);
        float var = l2[0] * (1.0f / 4096.0f) - mean * mean;
        float g = (c < csplit) ? g0[c] : g1[c - csplit];
        float be = (c < csplit) ? be0[c] : be1[c - csplit];
        float sc = g / sqrtf(var + 1e-5f);
        scale[c] = sc;
        shift[c] = be - mean * sc;
    }
}

// ---------------------------------------------------------------- mlp2: f1 = lrelu(feat*w + b); y_o = [f1,adf]@Wo + bo
__global__ __launch_bounds__(256) void mlp2_kernel(
        const float* __restrict__ y_wb,
        const float* __restrict__ scale1, const float* __restrict__ shift1,
        const float* __restrict__ feature, const int* __restrict__ sidx,
        const float* __restrict__ adf,
        const float* __restrict__ Wo, const float* __restrict__ bo,
        float* __restrict__ y_o) {
    __shared__ float sW[92 * 128];       // 47104 B
    __shared__ float t2[16 * 129];       // padded staging
    __shared__ float scat[16 * 92];      // cat rows
    int t = threadIdx.x;
    int s0 = blockIdx.x * 16;
    for (int i = t; i < 92 * 128; i += 256) sW[i] = Wo[i];
    for (int i = t; i < 16 * 128; i += 256) {
        int row = i & 15, c = i >> 4;
        t2[row * 129 + c] = fmaf(y_wb[c * 4096 + s0 + row], scale1[c], shift1[c]);
    }
    __syncthreads();
    for (int rr = 0; rr < 16; rr += 4) {
        int r = rr + (t >> 6);
        int c = t & 63;
        int si = sidx[s0 + r];
        float f = feature[si * 64 + c];
        float v = fmaf(f, t2[r * 129 + c], t2[r * 129 + 64 + c]);
        scat[r * 92 + c] = v >= 0.0f ? v : 0.2f * v;
    }
    for (int i = t; i < 16 * 28; i += 256) {
        int row = i / 28, k = i % 28;
        scat[row * 92 + 64 + k] = adf[(s0 + row) * 28 + k];
    }
    __syncthreads();
    int r = t >> 4, cg = t & 15;
    float acc[8];
#pragma unroll
    for (int j = 0; j < 8; ++j) acc[j] = bo[cg * 8 + j];
    for (int c = 0; c < 92; ++c) {
        float a = scat[r * 92 + c];
#pragma unroll
        for (int j = 0; j < 8; ++j)
            acc[j] = fmaf(a, sW[c * 128 + cg * 8 + j], acc[j]);
    }
    int s = s0 + r;
#pragma unroll
    for (int j = 0; j < 8; ++j) y_o[(cg * 8 + j) * 4096 + s] = acc[j];
}

// ---------------------------------------------------------------- final: normalize + lrelu, write feat
__global__ __launch_bounds__(256) void final_kernel(
        const float* __restrict__ y_o,
        const float* __restrict__ scale, const float* __restrict__ shift,
        float* __restrict__ out_feat) {
    int tid = blockIdx.x * 256 + threadIdx.x;  // 0..524287
    int j = tid >> 12;
    int s = tid & 4095;
    float v = fmaf(y_o[tid], scale[j], shift[j]);
    v = v >= 0.0f ? v : 0.2f * v;
    out_feat[s * 128 + j] = v;
}

// ----------------------------------------------------------------
extern "C" void kernel_launch(void* const* d_in, const int* in_sizes, int n_in,
                              void* d_out, int out_size, void* d_ws, size_t ws_size,
                              hipStream_t stream) {
    const float* xyz = (const float*)d_in[0];
    const float* feature = (const float*)d_in[1];
    const int* sidx = (const int*)d_in[2];
    const float* Ww = (const float*)d_in[3];
    const float* bw = (const float*)d_in[4];
    const float* gw = (const float*)d_in[5];
    const float* betaw = (const float*)d_in[6];
    const float* Wb = (const float*)d_in[7];
    const float* bb = (const float*)d_in[8];
    const float* gb = (const float*)d_in[9];
    const float* betab = (const float*)d_in[10];
    const float* Wo = (const float*)d_in[11];
    const float* bo = (const float*)d_in[12];
    const float* go = (const float*)d_in[13];
    const float* betao = (const float*)d_in[14];

    float* out = (float*)d_out;
    float* out_xyz = out;                                  // 4096*3
    float* out_feat = out + 12288;                         // 4096*128
    float* out_rf = out + 12288 + 524288;                  // 4096*16*28
    float* out_ni = out + 12288 + 524288 + 1835008;        // 4096*16

    float* ws = (float*)d_ws;
    float4* cb = (float4*)ws;                  // 8192 float4
    float4* ca = (float4*)(ws + 32768);        // 4096 float4
    int* a_before = (int*)(ws + 49152);        // 4096*4
    float* intra_before = ws + 65536;          // 4096*6
    int* ni_i = (int*)(ws + 90112);            // 4096*16
    float* intra_after = ws + 155648;          // 4096*6
    float* adf = ws + 180224;                  // 4096*28
    float* y_wb = ws + 294912;                 // 128*4096 (y_w then y_b)
    float* y_o = ws + 819200;                  // 128*4096
    float* scale1 = ws + 1343488;              // 128
    float* shift1 = ws + 1343616;              // 128
    float* scale_o = ws + 1343744;             // 128
    float* shift_o = ws + 1343872;             // 128

    stage_kernel<<<32, 256, 0, stream>>>(xyz, sidx, cb, ca, out_xyz);
    knn_kernel<<<2 * S_PTS, 256, 0, stream>>>(cb, ca, sidx, a_before, intra_before,
                                              ni_i, intra_after, out_ni);
    assemble_kernel<<<1024, 256, 0, stream>>>(ca, cb, ni_i, intra_after, a_before,
                                              intra_before, sidx, out_rf, adf);
    mlp1_kernel<<<128, 256, 0, stream>>>(adf, Ww, bw, Wb, bb, y_wb);
    stats_kernel<<<128, 256, 0, stream>>>(y_wb, gw, betaw, gb, betab, 64, scale1, shift1);
    mlp2_kernel<<<256, 256, 0, stream>>>(y_wb, scale1, shift1, feature, sidx, adf, Wo, bo, y_o);
    stats_kernel<<<128, 256, 0, stream>>>(y_o, go, betao, go, betao, 128, scale_o, shift_o);
    final_kernel<<<2048, 256, 0, stream>>>(y_o, scale_o, shift_o, out_feat);
}